// Round 15
// baseline (734.018 us; speedup 1.0000x reference)
//
#include <hip/hip_runtime.h>
#include <hip/hip_bf16.h>

typedef __bf16 bf16_t;
typedef _Float16 f16_t;
typedef __bf16 bf16x8 __attribute__((ext_vector_type(8)));
typedef _Float16 f16x8 __attribute__((ext_vector_type(8)));
typedef float  f32x4  __attribute__((ext_vector_type(4)));

#define GAS __attribute__((address_space(1)))
#define LAS __attribute__((address_space(3)))

__device__ __forceinline__ void gload_lds16(const void* g, void* l) {
    __builtin_amdgcn_global_load_lds((const GAS void*)g, (LAS void*)l, 16, 0, 0);
}

#define QSCALE 0.044194173824159216f  /* 1/sqrt(512) */
#define L2E    1.4426950408889634f

// ---------------- split fp32 -> (hi, lo) bf16 ----------------
__global__ __launch_bounds__(256) void k_split_x(const float* __restrict__ X,
                                                 bf16_t* __restrict__ H,
                                                 bf16_t* __restrict__ L, int n) {
    int i = (blockIdx.x * 256 + threadIdx.x) * 4;
    if (i >= n) return;
    float4 v = *(const float4*)(X + i);
    float vv[4] = {v.x, v.y, v.z, v.w};
    union { bf16_t b[4]; uint2 u; } hh, ll;
#pragma unroll
    for (int j = 0; j < 4; j++) {
        bf16_t h = (bf16_t)vv[j];
        hh.b[j] = h;
        ll.b[j] = (bf16_t)(vv[j] - (float)h);
    }
    *(uint2*)(H + i) = hh.u;
    *(uint2*)(L + i) = ll.u;
}

// ---------------- W[3,512,512] -> WT[3,512(o),512(d)] split ----------------
__global__ __launch_bounds__(256) void k_split_wt(const float* __restrict__ W,
                                                  bf16_t* __restrict__ H,
                                                  bf16_t* __restrict__ L) {
    int t = blockIdx.x * 256 + threadIdx.x;
    int base = t * 4;
    int m = base >> 18;
    int o = (base >> 9) & 511;
    int d = base & 511;
    union { bf16_t b[4]; uint2 u; } hh, ll;
#pragma unroll
    for (int j = 0; j < 4; j++) {
        float w = W[m * 262144 + (d + j) * 512 + o];
        bf16_t h = (bf16_t)w;
        hh.b[j] = h;
        ll.b[j] = (bf16_t)(w - (float)h);
    }
    *(uint2*)(H + base) = hh.u;
    *(uint2*)(L + base) = ll.u;
}

// -------- QKV projection GEMM-NT, 128x128 tile, BK=32 --------
// Q/K blocks: 3-pass split bf16 (fp32-class). V blocks: single hi*hi pass
// (bf16 accuracy suffices for V). Epilogue: Q fp16 (scaled), K fp16 hi/lo,
// V bf16 transposed.
__global__ __launch_bounds__(256) void k_qkv(
    const bf16_t* __restrict__ Ah, const bf16_t* __restrict__ Al,
    const bf16_t* __restrict__ Bh, const bf16_t* __restrict__ Bl,
    f16_t* __restrict__ Qf,
    f16_t* __restrict__ Kh, f16_t* __restrict__ Kl,
    bf16_t* __restrict__ VT) {
    __shared__ bf16_t lds[16384];
    bf16_t* As_h = lds;
    bf16_t* Bs_h = lds + 4096;
    bf16_t* As_l = lds + 8192;
    bf16_t* Bs_l = lds + 12288;

    const int tid = threadIdx.x;
    const int lane = tid & 63;
    const int wid = tid >> 6;
    const int wr = wid >> 1, wc = wid & 1;
    const size_t i0 = (size_t)blockIdx.y * 128;
    const size_t j0 = (size_t)blockIdx.x * 128;
    const int mat3 = (int)(j0 >> 9);      // 0=Q, 1=K, 2=V (uniform per block)
    const bool full = (mat3 != 2);

    const bf16_t* pAh = Ah + i0 * 512;
    const bf16_t* pBh = Bh + j0 * 512;
    const bf16_t* pAl = Al + i0 * 512;
    const bf16_t* pBl = Bl + j0 * 512;

    const int srow = tid >> 2;
    const int scoff = (tid & 3) * 8;

    f32x4 acc[4][4] = {};

    const int arow = wr * 64 + (lane & 15);
    const int brow = wc * 64 + (lane & 15);
    const int ko = (lane >> 4) * 8;

    for (int kt = 0; kt < 512; kt += 32) {
#pragma unroll
        for (int c = 0; c < 2; c++) {
            const size_t ra = (size_t)(c * 64 + srow) * 512 + kt + scoff;
            const int loff = c * 2048 + tid * 8;
            gload_lds16(pAh + ra, As_h + loff);
            gload_lds16(pBh + ra, Bs_h + loff);
            if (full) {
                gload_lds16(pAl + ra, As_l + loff);
                gload_lds16(pBl + ra, Bs_l + loff);
            }
        }
        __syncthreads();

        bf16x8 ah[4], bh[4];
#pragma unroll
        for (int m = 0; m < 4; m++) ah[m] = *(const bf16x8*)&As_h[(arow + m * 16) * 32 + ko];
#pragma unroll
        for (int n = 0; n < 4; n++) bh[n] = *(const bf16x8*)&Bs_h[(brow + n * 16) * 32 + ko];
        if (full) {
            bf16x8 al[4], bl[4];
#pragma unroll
            for (int m = 0; m < 4; m++) al[m] = *(const bf16x8*)&As_l[(arow + m * 16) * 32 + ko];
#pragma unroll
            for (int n = 0; n < 4; n++) bl[n] = *(const bf16x8*)&Bs_l[(brow + n * 16) * 32 + ko];
            __builtin_amdgcn_s_setprio(1);
#pragma unroll
            for (int m = 0; m < 4; m++)
#pragma unroll
                for (int n = 0; n < 4; n++) {
                    acc[m][n] = __builtin_amdgcn_mfma_f32_16x16x32_bf16(ah[m], bh[n], acc[m][n], 0, 0, 0);
                    acc[m][n] = __builtin_amdgcn_mfma_f32_16x16x32_bf16(ah[m], bl[n], acc[m][n], 0, 0, 0);
                    acc[m][n] = __builtin_amdgcn_mfma_f32_16x16x32_bf16(al[m], bh[n], acc[m][n], 0, 0, 0);
                }
            __builtin_amdgcn_s_setprio(0);
        } else {
            __builtin_amdgcn_s_setprio(1);
#pragma unroll
            for (int m = 0; m < 4; m++)
#pragma unroll
                for (int n = 0; n < 4; n++)
                    acc[m][n] = __builtin_amdgcn_mfma_f32_16x16x32_bf16(ah[m], bh[n], acc[m][n], 0, 0, 0);
            __builtin_amdgcn_s_setprio(0);
        }
        __syncthreads();
    }

#pragma unroll
    for (int m = 0; m < 4; m++) {
#pragma unroll
        for (int n = 0; n < 4; n++) {
#pragma unroll
            for (int j = 0; j < 4; j++) {
                const size_t gr = i0 + wr * 64 + m * 16 + (lane >> 4) * 4 + j;
                const size_t gc = j0 + wc * 64 + n * 16 + (lane & 15);
                float v = acc[m][n][j];
                const size_t bloc = gr >> 11;
                const size_t nrow = gr & 2047;
                const size_t o = gc & 511;
                const size_t idx = bloc * 1048576 + nrow * 512 + o;
                if (mat3 == 0) {
                    Qf[idx] = (f16_t)(v * QSCALE);
                } else if (mat3 == 1) {
                    f16_t h = (f16_t)v;
                    Kh[idx] = h; Kl[idx] = (f16_t)(v - (float)h);
                } else {
                    VT[bloc * 1048576 + o * 2048 + nrow] = (bf16_t)v;
                }
            }
        }
    }
}

// ---------------- fused flash attention (r11 + skip-rescale, VGPR>128) ----
// Grid (32, G). 512 thr / 8 waves. QBLK=64, KV tiles of 64.
// Q hoisted to REGISTERS. 4 QK phases/t of 128 cols (K hi/lo dbuf 2x32KB).
// V staged 2/8 per phase. Counted vmcnt. launch_bounds(512,1): min 1
// wave/EU lifts the default 128-VGPR cap (LDS already limits to 1 block/CU
// = 2 waves/SIMD, which is resident up to 256 VGPR) — this is what made
// the r13 skip-rescale spill; with headroom it is re-added here.
// Skip-rescale is EXACT (fr==1.0 when max unchanged).
#define KB_SZ   32768
#define VT_OFF  65536
#define PT_OFF  131072
#define MP_OFF  139264
#define SP_OFF  139776
#define MR_OFF  140288

__global__ __launch_bounds__(512, 1) void k_flash(
    const f16_t* __restrict__ Qf,
    const f16_t* __restrict__ Kh, const f16_t* __restrict__ Kl,
    const bf16_t* __restrict__ VT, float* __restrict__ Out) {
    __shared__ __align__(16) char smem[140800];

    const int tid = threadIdx.x;
    const int l = tid & 63, wid = tid >> 6;
    const int l15 = l & 15, l4 = l >> 4;
    const int rg4 = wid >> 1, kg = wid & 1;
    const int rg2 = wid >> 2, cg = wid & 3;

    // ---- XCD swizzle (bijective: total = 32G divisible by 8) ----
    const int total = gridDim.x * gridDim.y;
    const int f = blockIdx.x + gridDim.x * blockIdx.y;
    const int fp = (f & 7) * (total >> 3) + (f >> 3);
    const int b = fp >> 5;
    const int q0 = (fp & 31) * 64;
    const size_t NB = 1048576;

    const f16_t* qfb = Qf + (size_t)b * NB;
    const f16_t* khb = Kh + (size_t)b * NB;
    const f16_t* klb = Kl + (size_t)b * NB;
    const bf16_t* vtb = VT + (size_t)b * NB;

    float* MP = (float*)(smem + MP_OFF);   // [2][64] tile-max partials
    float* SP = (float*)(smem + SP_OFF);   // [2][64] exp-sum partials
    float* MR = (float*)(smem + MR_OFF);   // [2][64] running max, ping-pong

    if (tid < 128) MR[tid] = -3e38f;

    f32x4 O[2][8] = {};
    float mreg[2][4], lreg[2][4];
#pragma unroll
    for (int mf = 0; mf < 2; mf++)
#pragma unroll
        for (int j = 0; j < 4; j++) { mreg[mf][j] = -3e38f; lreg[mf][j] = 0.f; }

    const int srow = tid >> 3;
    const int sgl = (tid & 7) ^ (srow & 7);
    const int gsw = l15 & 7;

    // stage K 128-col chunk kc2 (two 64-col subchunks, hi+lo) into buffer b2
    auto stage_k = [&](int t, int kc2, int b2) {
#pragma unroll
        for (int sub = 0; sub < 2; sub++) {
            const int co = kc2 * 128 + sub * 64 + sgl * 8;
            f16_t* d = (f16_t*)(smem + b2 * KB_SZ + sub * 16384) + tid * 8;
            gload_lds16(khb + (size_t)(t * 64 + srow) * 512 + co, d);
            gload_lds16(klb + (size_t)(t * 64 + srow) * 512 + co, d + 4096);
        }
    };
    // stage V^T eighth j (of 8) for kv-tile t
    auto stage_v = [&](int t, int j) {
        const int g = j * 512 + tid;
        const int orow = g >> 3;
        const int gl = (g & 7) ^ (orow & 7);
        gload_lds16(vtb + (size_t)orow * 2048 + t * 64 + gl * 8,
                    (bf16_t*)(smem + VT_OFF + g * 16));
    };

    // ---- prologue: Q -> LDS (via V area) -> registers; stage K chunk 0 ----
#pragma unroll
    for (int qc = 0; qc < 8; qc++) {
        const int co = qc * 64 + sgl * 8;
        gload_lds16(qfb + (size_t)(q0 + srow) * 512 + co,
                    (f16_t*)(smem + VT_OFF + qc * 8192) + tid * 8);
    }
    stage_k(0, 0, 0);
    asm volatile("s_waitcnt vmcnt(4)" ::: "memory");
    __builtin_amdgcn_s_barrier();

    f16x8 qreg[16];
    const int arow = rg4 * 16 + l15;
#pragma unroll
    for (int qc = 0; qc < 8; qc++)
#pragma unroll
        for (int ks = 0; ks < 2; ks++) {
            const int gph = ((ks * 4 + l4) ^ gsw) << 4;
            qreg[qc * 2 + ks] = *(const f16x8*)(smem + VT_OFF + qc * 8192 + arow * 128 + gph);
        }
    asm volatile("s_waitcnt lgkmcnt(0)" ::: "memory");
    __builtin_amdgcn_s_barrier();

#pragma unroll 1
    for (int t = 0; t < 32; t++) {
        f32x4 S[2] = {};
#pragma unroll
        for (int kc2 = 0; kc2 < 4; kc2++) {
            if (kc2 == 0) asm volatile("s_waitcnt vmcnt(0)" ::: "memory");
            else          asm volatile("s_waitcnt vmcnt(2)" ::: "memory");
            __builtin_amdgcn_s_barrier();
            if (kc2 < 3) {
                stage_k(t, kc2 + 1, (kc2 + 1) & 1);
                stage_v(t, kc2 * 2);
                stage_v(t, kc2 * 2 + 1);
            } else {
                stage_v(t, 6);
                stage_v(t, 7);
                if (t < 31) stage_k(t + 1, 0, 0);
            }
            // compute chunk kc2 from buf kc2&1: S += Q*Kh + Q*Kl
            const char* CB = smem + (kc2 & 1) * KB_SZ;
#pragma unroll
            for (int sub = 0; sub < 2; sub++)
#pragma unroll
                for (int ks = 0; ks < 2; ks++) {
                    const int gph = ((ks * 4 + l4) ^ gsw) << 4;
                    f16x8 qa = qreg[kc2 * 4 + sub * 2 + ks];
                    __builtin_amdgcn_s_setprio(1);
#pragma unroll
                    for (int nf = 0; nf < 2; nf++) {
                        const int brow = kg * 32 + nf * 16 + l15;
                        f16x8 bh = *(const f16x8*)(CB + sub * 16384 + brow * 128 + gph);
                        f16x8 bl = *(const f16x8*)(CB + sub * 16384 + 8192 + brow * 128 + gph);
                        S[nf] = __builtin_amdgcn_mfma_f32_16x16x32_f16(qa, bh, S[nf], 0, 0, 0);
                        S[nf] = __builtin_amdgcn_mfma_f32_16x16x32_f16(qa, bl, S[nf], 0, 0, 0);
                    }
                    __builtin_amdgcn_s_setprio(0);
                }
        }

        // ---- online softmax (cross-wave via LDS) ----
        const int rb4 = rg4 * 16 + l4 * 4;
        float pm[4];
#pragma unroll
        for (int j = 0; j < 4; j++) pm[j] = fmaxf(S[0][j], S[1][j]);
#pragma unroll
        for (int off = 1; off < 16; off <<= 1)
#pragma unroll
            for (int j = 0; j < 4; j++) pm[j] = fmaxf(pm[j], __shfl_xor(pm[j], off));
        if (l15 == 0) {
            f32x4 v; v[0] = pm[0]; v[1] = pm[1]; v[2] = pm[2]; v[3] = pm[3];
            *(f32x4*)(MP + kg * 64 + rb4) = v;
        }
        asm volatile("s_waitcnt lgkmcnt(0)" ::: "memory");
        __builtin_amdgcn_s_barrier();

        f32x4 mp0 = *(const f32x4*)(MP + rb4);
        f32x4 mp1 = *(const f32x4*)(MP + 64 + rb4);
        f32x4 mold = *(const f32x4*)(MR + (t & 1) * 64 + rb4);
        float mnew[4];
#pragma unroll
        for (int j = 0; j < 4; j++) mnew[j] = fmaxf(mold[j], fmaxf(mp0[j], mp1[j]));
        if (kg == 0 && l15 == 0) {
            f32x4 v; v[0] = mnew[0]; v[1] = mnew[1]; v[2] = mnew[2]; v[3] = mnew[3];
            *(f32x4*)(MR + ((t + 1) & 1) * 64 + rb4) = v;
        }
        float p[2][4], ps[4];
#pragma unroll
        for (int nf = 0; nf < 2; nf++)
#pragma unroll
            for (int j = 0; j < 4; j++) p[nf][j] = exp2f((S[nf][j] - mnew[j]) * L2E);
#pragma unroll
        for (int j = 0; j < 4; j++) ps[j] = p[0][j] + p[1][j];
#pragma unroll
        for (int off = 1; off < 16; off <<= 1)
#pragma unroll
            for (int j = 0; j < 4; j++) ps[j] += __shfl_xor(ps[j], off);
        if (l15 == 0) {
            f32x4 v; v[0] = ps[0]; v[1] = ps[1]; v[2] = ps[2]; v[3] = ps[3];
            *(f32x4*)(SP + kg * 64 + rb4) = v;
        }
        // P -> bf16 into swizzled LDS tile [64 rows][128 B]
#pragma unroll
        for (int nf = 0; nf < 2; nf++)
#pragma unroll
            for (int j = 0; j < 4; j++) {
                const int row = rb4 + j;
                const int phys = (kg * 4 + nf * 2 + (l15 >> 3)) ^ (row & 7);
                *(bf16_t*)(smem + PT_OFF + row * 128 + phys * 16 + (l15 & 7) * 2) =
                    (bf16_t)p[nf][j];
            }
        if (t < 31) asm volatile("s_waitcnt vmcnt(4) lgkmcnt(0)" ::: "memory");
        else        asm volatile("s_waitcnt vmcnt(0) lgkmcnt(0)" ::: "memory");
        __builtin_amdgcn_s_barrier();

        // ---- PV: rescale O (exact skip when running max unchanged) ----
        {
            f32x4 mn2[2], spv[2];
            bool chg = false;
#pragma unroll
            for (int mf = 0; mf < 2; mf++) {
                const int rb = rg2 * 32 + mf * 16 + l4 * 4;
                mn2[mf] = *(const f32x4*)(MR + ((t + 1) & 1) * 64 + rb);
                f32x4 sp0 = *(const f32x4*)(SP + rb);
                f32x4 sp1 = *(const f32x4*)(SP + 64 + rb);
#pragma unroll
                for (int j = 0; j < 4; j++) {
                    spv[mf][j] = sp0[j] + sp1[j];
                    if (mn2[mf][j] > mreg[mf][j]) chg = true;
                }
            }
            if (__any(chg)) {
#pragma unroll
                for (int mf = 0; mf < 2; mf++) {
                    float fr[4];
#pragma unroll
                    for (int j = 0; j < 4; j++) {
                        fr[j] = exp2f((mreg[mf][j] - mn2[mf][j]) * L2E);
                        lreg[mf][j] = lreg[mf][j] * fr[j] + spv[mf][j];
                        mreg[mf][j] = mn2[mf][j];
                    }
#pragma unroll
                    for (int nf = 0; nf < 8; nf++)
#pragma unroll
                        for (int j = 0; j < 4; j++) O[mf][nf][j] *= fr[j];
                }
            } else {
#pragma unroll
                for (int mf = 0; mf < 2; mf++)
#pragma unroll
                    for (int j = 0; j < 4; j++) lreg[mf][j] += spv[mf][j];
            }
        }
#pragma unroll
        for (int ks = 0; ks < 2; ks++) {
            const int gph = ((ks * 4 + l4) ^ gsw) << 4;
            bf16x8 pa[2];
#pragma unroll
            for (int mf = 0; mf < 2; mf++) {
                const int prow = rg2 * 32 + mf * 16 + l15;
                pa[mf] = *(const bf16x8*)(smem + PT_OFF + prow * 128 + gph);
            }
            __builtin_amdgcn_s_setprio(1);
#pragma unroll
            for (int nf = 0; nf < 8; nf++) {
                const int vrow = cg * 128 + nf * 16 + l15;
                bf16x8 vb = *(const bf16x8*)(smem + VT_OFF + vrow * 128 + gph);
#pragma unroll
                for (int mf = 0; mf < 2; mf++)
                    O[mf][nf] = __builtin_amdgcn_mfma_f32_16x16x32_bf16(pa[mf], vb, O[mf][nf], 0, 0, 0);
            }
            __builtin_amdgcn_s_setprio(0);
        }
    }

    // ---- epilogue: O / l ----
#pragma unroll
    for (int mf = 0; mf < 2; mf++) {
        float inv[4];
#pragma unroll
        for (int j = 0; j < 4; j++) inv[j] = 1.0f / lreg[mf][j];
#pragma unroll
        for (int nf = 0; nf < 8; nf++)
#pragma unroll
            for (int j = 0; j < 4; j++) {
                const size_t row = q0 + rg2 * 32 + mf * 16 + l4 * 4 + j;
                const size_t col = cg * 128 + nf * 16 + l15;
                Out[(size_t)b * NB + row * 512 + col] = O[mf][nf][j] * inv[j];
            }
    }
}

extern "C" void kernel_launch(void* const* d_in, const int* in_sizes, int n_in,
                              void* d_out, int out_size, void* d_ws, size_t ws_size,
                              hipStream_t stream) {
    const float* x = (const float*)d_in[0];
    const float* w = (const float*)d_in[1];
    float* out = (float*)d_out;

    const size_t NB = (size_t)2048 * 512;
    const size_t NW = (size_t)3 * 512 * 512;

    const size_t perG = 6 * NB * 2;   // xh,xl,qf,kh,kl,vt @ 2 MB each
    size_t fixed = 2 * NW * 2 + 4096;
    int G = 1;
    if (ws_size > fixed + perG) {
        size_t g = (ws_size - fixed) / perG;
        G = (int)(g > 16 ? 16 : g);
    } else {
        return;  // workspace too small (needs ~15 MB)
    }

    size_t off = 0;
    char* wsb = (char*)d_ws;
    auto take = [&](size_t bytes) -> char* {
        char* p = wsb + off;
        off = (off + bytes + 255) & ~(size_t)255;
        return p;
    };
    bf16_t* wth = (bf16_t*)take(NW * 2);
    bf16_t* wtl = (bf16_t*)take(NW * 2);
    bf16_t* xh = (bf16_t*)take(G * NB * 2);
    bf16_t* xl = (bf16_t*)take(G * NB * 2);
    f16_t*  qf = (f16_t*)take(G * NB * 2);
    f16_t*  kh = (f16_t*)take(G * NB * 2);
    f16_t*  kl = (f16_t*)take(G * NB * 2);
    bf16_t* vt = (bf16_t*)take(G * NB * 2);

    k_split_wt<<<dim3((unsigned)(NW / 4 / 256)), 256, 0, stream>>>(w, wth, wtl);

    for (int g0 = 0; g0 < 16; g0 += G) {
        const int Gc = (16 - g0 < G) ? (16 - g0) : G;
        const size_t base = (size_t)g0 * NB;
        k_split_x<<<dim3((unsigned)(Gc * NB / 4 / 256)), 256, 0, stream>>>(
            x + base, xh, xl, (int)(Gc * NB));
        k_qkv<<<dim3(12, 16 * Gc), 256, 0, stream>>>(
            xh, xl, wth, wtl, qf, kh, kl, vt);
        k_flash<<<dim3(32, Gc), 512, 0, stream>>>(
            qf, kh, kl, vt, out + base);
    }
}

// Round 16
// 559.894 us; speedup vs baseline: 1.3110x; 1.3110x over previous
//
#include <hip/hip_runtime.h>
#include <hip/hip_bf16.h>

typedef __bf16 bf16_t;
typedef _Float16 f16_t;
typedef __bf16 bf16x8 __attribute__((ext_vector_type(8)));
typedef _Float16 f16x8 __attribute__((ext_vector_type(8)));
typedef float  f32x4  __attribute__((ext_vector_type(4)));

#define GAS __attribute__((address_space(1)))
#define LAS __attribute__((address_space(3)))

__device__ __forceinline__ void gload_lds16(const void* g, void* l) {
    __builtin_amdgcn_global_load_lds((const GAS void*)g, (LAS void*)l, 16, 0, 0);
}

#define QSCALE 0.044194173824159216f  /* 1/sqrt(512) */
#define L2E    1.4426950408889634f

// ---------------- split fp32 -> (hi, lo) bf16 ----------------
__global__ __launch_bounds__(256) void k_split_x(const float* __restrict__ X,
                                                 bf16_t* __restrict__ H,
                                                 bf16_t* __restrict__ L, int n) {
    int i = (blockIdx.x * 256 + threadIdx.x) * 4;
    if (i >= n) return;
    float4 v = *(const float4*)(X + i);
    float vv[4] = {v.x, v.y, v.z, v.w};
    union { bf16_t b[4]; uint2 u; } hh, ll;
#pragma unroll
    for (int j = 0; j < 4; j++) {
        bf16_t h = (bf16_t)vv[j];
        hh.b[j] = h;
        ll.b[j] = (bf16_t)(vv[j] - (float)h);
    }
    *(uint2*)(H + i) = hh.u;
    *(uint2*)(L + i) = ll.u;
}

// ---------------- W[3,512,512] -> WT[3,512(o),512(d)] split ----------------
__global__ __launch_bounds__(256) void k_split_wt(const float* __restrict__ W,
                                                  bf16_t* __restrict__ H,
                                                  bf16_t* __restrict__ L) {
    int t = blockIdx.x * 256 + threadIdx.x;
    int base = t * 4;
    int m = base >> 18;
    int o = (base >> 9) & 511;
    int d = base & 511;
    union { bf16_t b[4]; uint2 u; } hh, ll;
#pragma unroll
    for (int j = 0; j < 4; j++) {
        float w = W[m * 262144 + (d + j) * 512 + o];
        bf16_t h = (bf16_t)w;
        hh.b[j] = h;
        ll.b[j] = (bf16_t)(w - (float)h);
    }
    *(uint2*)(H + base) = hh.u;
    *(uint2*)(L + base) = ll.u;
}

// -------- QKV projection GEMM-NT, 128x128 tile, BK=32 --------
// Q/K blocks: 3-pass split bf16 (fp32-class). V blocks: single hi*hi pass
// (bf16 accuracy suffices for V). Epilogue: Q fp16 (scaled), K fp16 hi/lo,
// V bf16 transposed.
__global__ __launch_bounds__(256) void k_qkv(
    const bf16_t* __restrict__ Ah, const bf16_t* __restrict__ Al,
    const bf16_t* __restrict__ Bh, const bf16_t* __restrict__ Bl,
    f16_t* __restrict__ Qf,
    f16_t* __restrict__ Kh, f16_t* __restrict__ Kl,
    bf16_t* __restrict__ VT) {
    __shared__ bf16_t lds[16384];
    bf16_t* As_h = lds;
    bf16_t* Bs_h = lds + 4096;
    bf16_t* As_l = lds + 8192;
    bf16_t* Bs_l = lds + 12288;

    const int tid = threadIdx.x;
    const int lane = tid & 63;
    const int wid = tid >> 6;
    const int wr = wid >> 1, wc = wid & 1;
    const size_t i0 = (size_t)blockIdx.y * 128;
    const size_t j0 = (size_t)blockIdx.x * 128;
    const int mat3 = (int)(j0 >> 9);      // 0=Q, 1=K, 2=V (uniform per block)
    const bool full = (mat3 != 2);

    const bf16_t* pAh = Ah + i0 * 512;
    const bf16_t* pBh = Bh + j0 * 512;
    const bf16_t* pAl = Al + i0 * 512;
    const bf16_t* pBl = Bl + j0 * 512;

    const int srow = tid >> 2;
    const int scoff = (tid & 3) * 8;

    f32x4 acc[4][4] = {};

    const int arow = wr * 64 + (lane & 15);
    const int brow = wc * 64 + (lane & 15);
    const int ko = (lane >> 4) * 8;

    for (int kt = 0; kt < 512; kt += 32) {
#pragma unroll
        for (int c = 0; c < 2; c++) {
            const size_t ra = (size_t)(c * 64 + srow) * 512 + kt + scoff;
            const int loff = c * 2048 + tid * 8;
            gload_lds16(pAh + ra, As_h + loff);
            gload_lds16(pBh + ra, Bs_h + loff);
            if (full) {
                gload_lds16(pAl + ra, As_l + loff);
                gload_lds16(pBl + ra, Bs_l + loff);
            }
        }
        __syncthreads();

        bf16x8 ah[4], bh[4];
#pragma unroll
        for (int m = 0; m < 4; m++) ah[m] = *(const bf16x8*)&As_h[(arow + m * 16) * 32 + ko];
#pragma unroll
        for (int n = 0; n < 4; n++) bh[n] = *(const bf16x8*)&Bs_h[(brow + n * 16) * 32 + ko];
        if (full) {
            bf16x8 al[4], bl[4];
#pragma unroll
            for (int m = 0; m < 4; m++) al[m] = *(const bf16x8*)&As_l[(arow + m * 16) * 32 + ko];
#pragma unroll
            for (int n = 0; n < 4; n++) bl[n] = *(const bf16x8*)&Bs_l[(brow + n * 16) * 32 + ko];
            __builtin_amdgcn_s_setprio(1);
#pragma unroll
            for (int m = 0; m < 4; m++)
#pragma unroll
                for (int n = 0; n < 4; n++) {
                    acc[m][n] = __builtin_amdgcn_mfma_f32_16x16x32_bf16(ah[m], bh[n], acc[m][n], 0, 0, 0);
                    acc[m][n] = __builtin_amdgcn_mfma_f32_16x16x32_bf16(ah[m], bl[n], acc[m][n], 0, 0, 0);
                    acc[m][n] = __builtin_amdgcn_mfma_f32_16x16x32_bf16(al[m], bh[n], acc[m][n], 0, 0, 0);
                }
            __builtin_amdgcn_s_setprio(0);
        } else {
            __builtin_amdgcn_s_setprio(1);
#pragma unroll
            for (int m = 0; m < 4; m++)
#pragma unroll
                for (int n = 0; n < 4; n++)
                    acc[m][n] = __builtin_amdgcn_mfma_f32_16x16x32_bf16(ah[m], bh[n], acc[m][n], 0, 0, 0);
            __builtin_amdgcn_s_setprio(0);
        }
        __syncthreads();
    }

#pragma unroll
    for (int m = 0; m < 4; m++) {
#pragma unroll
        for (int n = 0; n < 4; n++) {
#pragma unroll
            for (int j = 0; j < 4; j++) {
                const size_t gr = i0 + wr * 64 + m * 16 + (lane >> 4) * 4 + j;
                const size_t gc = j0 + wc * 64 + n * 16 + (lane & 15);
                float v = acc[m][n][j];
                const size_t bloc = gr >> 11;
                const size_t nrow = gr & 2047;
                const size_t o = gc & 511;
                const size_t idx = bloc * 1048576 + nrow * 512 + o;
                if (mat3 == 0) {
                    Qf[idx] = (f16_t)(v * QSCALE);
                } else if (mat3 == 1) {
                    f16_t h = (f16_t)v;
                    Kh[idx] = h; Kl[idx] = (f16_t)(v - (float)h);
                } else {
                    VT[bloc * 1048576 + o * 2048 + nrow] = (bf16_t)v;
                }
            }
        }
    }
}

// ---------------- fused flash attention (r11/r14, verified 383 us) ---------
// Grid (32, G). 512 thr / 8 waves. QBLK=64, KV tiles of 64.
// Q hoisted to REGISTERS (16 f16x8/lane, loop-invariant across all 32 t).
// 4 QK phases/t of 128 cols (K hi/lo dbuf 2x32KB). V staged 2/8 per phase.
// Counted vmcnt: entry vmcnt(2), pre-PV vmcnt(4); no mid-loop drains.
// NOTE: unconditional O-rescale. 512-thread blocks are HARD-CAPPED at 128
// VGPR/wave on gfx950 (confirmed r13 AND r15 — launch_bounds(512,1) does
// NOT lift it); the skip-rescale variant spills the O accumulator
// (WRITE_SIZE 65->101 MB, flash 383->556 us). Do not reintroduce.
#define KB_SZ   32768
#define VT_OFF  65536
#define PT_OFF  131072
#define MP_OFF  139264
#define SP_OFF  139776
#define MR_OFF  140288

__global__ __launch_bounds__(512) void k_flash(
    const f16_t* __restrict__ Qf,
    const f16_t* __restrict__ Kh, const f16_t* __restrict__ Kl,
    const bf16_t* __restrict__ VT, float* __restrict__ Out) {
    __shared__ __align__(16) char smem[140800];

    const int tid = threadIdx.x;
    const int l = tid & 63, wid = tid >> 6;
    const int l15 = l & 15, l4 = l >> 4;
    const int rg4 = wid >> 1, kg = wid & 1;
    const int rg2 = wid >> 2, cg = wid & 3;

    // ---- XCD swizzle (bijective: total = 32G divisible by 8) ----
    const int total = gridDim.x * gridDim.y;
    const int f = blockIdx.x + gridDim.x * blockIdx.y;
    const int fp = (f & 7) * (total >> 3) + (f >> 3);
    const int b = fp >> 5;
    const int q0 = (fp & 31) * 64;
    const size_t NB = 1048576;

    const f16_t* qfb = Qf + (size_t)b * NB;
    const f16_t* khb = Kh + (size_t)b * NB;
    const f16_t* klb = Kl + (size_t)b * NB;
    const bf16_t* vtb = VT + (size_t)b * NB;

    float* MP = (float*)(smem + MP_OFF);   // [2][64] tile-max partials
    float* SP = (float*)(smem + SP_OFF);   // [2][64] exp-sum partials
    float* MR = (float*)(smem + MR_OFF);   // [2][64] running max, ping-pong

    if (tid < 128) MR[tid] = -3e38f;

    f32x4 O[2][8] = {};
    float mreg[2][4], lreg[2][4];
#pragma unroll
    for (int mf = 0; mf < 2; mf++)
#pragma unroll
        for (int j = 0; j < 4; j++) { mreg[mf][j] = -3e38f; lreg[mf][j] = 0.f; }

    const int srow = tid >> 3;
    const int sgl = (tid & 7) ^ (srow & 7);
    const int gsw = l15 & 7;

    // stage K 128-col chunk kc2 (two 64-col subchunks, hi+lo) into buffer b2
    auto stage_k = [&](int t, int kc2, int b2) {
#pragma unroll
        for (int sub = 0; sub < 2; sub++) {
            const int co = kc2 * 128 + sub * 64 + sgl * 8;
            f16_t* d = (f16_t*)(smem + b2 * KB_SZ + sub * 16384) + tid * 8;
            gload_lds16(khb + (size_t)(t * 64 + srow) * 512 + co, d);
            gload_lds16(klb + (size_t)(t * 64 + srow) * 512 + co, d + 4096);
        }
    };
    // stage V^T eighth j (of 8) for kv-tile t
    auto stage_v = [&](int t, int j) {
        const int g = j * 512 + tid;
        const int orow = g >> 3;
        const int gl = (g & 7) ^ (orow & 7);
        gload_lds16(vtb + (size_t)orow * 2048 + t * 64 + gl * 8,
                    (bf16_t*)(smem + VT_OFF + g * 16));
    };

    // ---- prologue: Q -> LDS (via V area) -> registers; stage K chunk 0 ----
#pragma unroll
    for (int qc = 0; qc < 8; qc++) {
        const int co = qc * 64 + sgl * 8;
        gload_lds16(qfb + (size_t)(q0 + srow) * 512 + co,
                    (f16_t*)(smem + VT_OFF + qc * 8192) + tid * 8);
    }
    stage_k(0, 0, 0);
    asm volatile("s_waitcnt vmcnt(4)" ::: "memory");
    __builtin_amdgcn_s_barrier();

    f16x8 qreg[16];
    const int arow = rg4 * 16 + l15;
#pragma unroll
    for (int qc = 0; qc < 8; qc++)
#pragma unroll
        for (int ks = 0; ks < 2; ks++) {
            const int gph = ((ks * 4 + l4) ^ gsw) << 4;
            qreg[qc * 2 + ks] = *(const f16x8*)(smem + VT_OFF + qc * 8192 + arow * 128 + gph);
        }
    asm volatile("s_waitcnt lgkmcnt(0)" ::: "memory");
    __builtin_amdgcn_s_barrier();

#pragma unroll 1
    for (int t = 0; t < 32; t++) {
        f32x4 S[2] = {};
#pragma unroll
        for (int kc2 = 0; kc2 < 4; kc2++) {
            if (kc2 == 0) asm volatile("s_waitcnt vmcnt(0)" ::: "memory");
            else          asm volatile("s_waitcnt vmcnt(2)" ::: "memory");
            __builtin_amdgcn_s_barrier();
            if (kc2 < 3) {
                stage_k(t, kc2 + 1, (kc2 + 1) & 1);
                stage_v(t, kc2 * 2);
                stage_v(t, kc2 * 2 + 1);
            } else {
                stage_v(t, 6);
                stage_v(t, 7);
                if (t < 31) stage_k(t + 1, 0, 0);
            }
            // compute chunk kc2 from buf kc2&1: S += Q*Kh + Q*Kl
            const char* CB = smem + (kc2 & 1) * KB_SZ;
#pragma unroll
            for (int sub = 0; sub < 2; sub++)
#pragma unroll
                for (int ks = 0; ks < 2; ks++) {
                    const int gph = ((ks * 4 + l4) ^ gsw) << 4;
                    f16x8 qa = qreg[kc2 * 4 + sub * 2 + ks];
                    __builtin_amdgcn_s_setprio(1);
#pragma unroll
                    for (int nf = 0; nf < 2; nf++) {
                        const int brow = kg * 32 + nf * 16 + l15;
                        f16x8 bh = *(const f16x8*)(CB + sub * 16384 + brow * 128 + gph);
                        f16x8 bl = *(const f16x8*)(CB + sub * 16384 + 8192 + brow * 128 + gph);
                        S[nf] = __builtin_amdgcn_mfma_f32_16x16x32_f16(qa, bh, S[nf], 0, 0, 0);
                        S[nf] = __builtin_amdgcn_mfma_f32_16x16x32_f16(qa, bl, S[nf], 0, 0, 0);
                    }
                    __builtin_amdgcn_s_setprio(0);
                }
        }

        // ---- online softmax (cross-wave via LDS) ----
        const int rb4 = rg4 * 16 + l4 * 4;
        float pm[4];
#pragma unroll
        for (int j = 0; j < 4; j++) pm[j] = fmaxf(S[0][j], S[1][j]);
#pragma unroll
        for (int off = 1; off < 16; off <<= 1)
#pragma unroll
            for (int j = 0; j < 4; j++) pm[j] = fmaxf(pm[j], __shfl_xor(pm[j], off));
        if (l15 == 0) {
            f32x4 v; v[0] = pm[0]; v[1] = pm[1]; v[2] = pm[2]; v[3] = pm[3];
            *(f32x4*)(MP + kg * 64 + rb4) = v;
        }
        asm volatile("s_waitcnt lgkmcnt(0)" ::: "memory");
        __builtin_amdgcn_s_barrier();

        f32x4 mp0 = *(const f32x4*)(MP + rb4);
        f32x4 mp1 = *(const f32x4*)(MP + 64 + rb4);
        f32x4 mold = *(const f32x4*)(MR + (t & 1) * 64 + rb4);
        float mnew[4];
#pragma unroll
        for (int j = 0; j < 4; j++) mnew[j] = fmaxf(mold[j], fmaxf(mp0[j], mp1[j]));
        if (kg == 0 && l15 == 0) {
            f32x4 v; v[0] = mnew[0]; v[1] = mnew[1]; v[2] = mnew[2]; v[3] = mnew[3];
            *(f32x4*)(MR + ((t + 1) & 1) * 64 + rb4) = v;
        }
        float p[2][4], ps[4];
#pragma unroll
        for (int nf = 0; nf < 2; nf++)
#pragma unroll
            for (int j = 0; j < 4; j++) p[nf][j] = exp2f((S[nf][j] - mnew[j]) * L2E);
#pragma unroll
        for (int j = 0; j < 4; j++) ps[j] = p[0][j] + p[1][j];
#pragma unroll
        for (int off = 1; off < 16; off <<= 1)
#pragma unroll
            for (int j = 0; j < 4; j++) ps[j] += __shfl_xor(ps[j], off);
        if (l15 == 0) {
            f32x4 v; v[0] = ps[0]; v[1] = ps[1]; v[2] = ps[2]; v[3] = ps[3];
            *(f32x4*)(SP + kg * 64 + rb4) = v;
        }
        // P -> bf16 into swizzled LDS tile [64 rows][128 B]
#pragma unroll
        for (int nf = 0; nf < 2; nf++)
#pragma unroll
            for (int j = 0; j < 4; j++) {
                const int row = rb4 + j;
                const int phys = (kg * 4 + nf * 2 + (l15 >> 3)) ^ (row & 7);
                *(bf16_t*)(smem + PT_OFF + row * 128 + phys * 16 + (l15 & 7) * 2) =
                    (bf16_t)p[nf][j];
            }
        if (t < 31) asm volatile("s_waitcnt vmcnt(4) lgkmcnt(0)" ::: "memory");
        else        asm volatile("s_waitcnt vmcnt(0) lgkmcnt(0)" ::: "memory");
        __builtin_amdgcn_s_barrier();

        // ---- PV: rescale O, accumulate P*V ----
#pragma unroll
        for (int mf = 0; mf < 2; mf++) {
            const int rb = rg2 * 32 + mf * 16 + l4 * 4;
            f32x4 mn = *(const f32x4*)(MR + ((t + 1) & 1) * 64 + rb);
            f32x4 sp0 = *(const f32x4*)(SP + rb);
            f32x4 sp1 = *(const f32x4*)(SP + 64 + rb);
            float fr[4];
#pragma unroll
            for (int j = 0; j < 4; j++) {
                fr[j] = exp2f((mreg[mf][j] - mn[j]) * L2E);
                lreg[mf][j] = lreg[mf][j] * fr[j] + sp0[j] + sp1[j];
                mreg[mf][j] = mn[j];
            }
#pragma unroll
            for (int nf = 0; nf < 8; nf++)
#pragma unroll
                for (int j = 0; j < 4; j++) O[mf][nf][j] *= fr[j];
        }
#pragma unroll
        for (int ks = 0; ks < 2; ks++) {
            const int gph = ((ks * 4 + l4) ^ gsw) << 4;
            bf16x8 pa[2];
#pragma unroll
            for (int mf = 0; mf < 2; mf++) {
                const int prow = rg2 * 32 + mf * 16 + l15;
                pa[mf] = *(const bf16x8*)(smem + PT_OFF + prow * 128 + gph);
            }
            __builtin_amdgcn_s_setprio(1);
#pragma unroll
            for (int nf = 0; nf < 8; nf++) {
                const int vrow = cg * 128 + nf * 16 + l15;
                bf16x8 vb = *(const bf16x8*)(smem + VT_OFF + vrow * 128 + gph);
#pragma unroll
                for (int mf = 0; mf < 2; mf++)
                    O[mf][nf] = __builtin_amdgcn_mfma_f32_16x16x32_bf16(pa[mf], vb, O[mf][nf], 0, 0, 0);
            }
            __builtin_amdgcn_s_setprio(0);
        }
    }

    // ---- epilogue: O / l ----
#pragma unroll
    for (int mf = 0; mf < 2; mf++) {
        float inv[4];
#pragma unroll
        for (int j = 0; j < 4; j++) inv[j] = 1.0f / lreg[mf][j];
#pragma unroll
        for (int nf = 0; nf < 8; nf++)
#pragma unroll
            for (int j = 0; j < 4; j++) {
                const size_t row = q0 + rg2 * 32 + mf * 16 + l4 * 4 + j;
                const size_t col = cg * 128 + nf * 16 + l15;
                Out[(size_t)b * NB + row * 512 + col] = O[mf][nf][j] * inv[j];
            }
    }
}

extern "C" void kernel_launch(void* const* d_in, const int* in_sizes, int n_in,
                              void* d_out, int out_size, void* d_ws, size_t ws_size,
                              hipStream_t stream) {
    const float* x = (const float*)d_in[0];
    const float* w = (const float*)d_in[1];
    float* out = (float*)d_out;

    const size_t NB = (size_t)2048 * 512;
    const size_t NW = (size_t)3 * 512 * 512;

    const size_t perG = 6 * NB * 2;   // xh,xl,qf,kh,kl,vt @ 2 MB each
    size_t fixed = 2 * NW * 2 + 4096;
    int G = 1;
    if (ws_size > fixed + perG) {
        size_t g = (ws_size - fixed) / perG;
        G = (int)(g > 16 ? 16 : g);
    } else {
        return;  // workspace too small (needs ~15 MB)
    }

    size_t off = 0;
    char* wsb = (char*)d_ws;
    auto take = [&](size_t bytes) -> char* {
        char* p = wsb + off;
        off = (off + bytes + 255) & ~(size_t)255;
        return p;
    };
    bf16_t* wth = (bf16_t*)take(NW * 2);
    bf16_t* wtl = (bf16_t*)take(NW * 2);
    bf16_t* xh = (bf16_t*)take(G * NB * 2);
    bf16_t* xl = (bf16_t*)take(G * NB * 2);
    f16_t*  qf = (f16_t*)take(G * NB * 2);
    f16_t*  kh = (f16_t*)take(G * NB * 2);
    f16_t*  kl = (f16_t*)take(G * NB * 2);
    bf16_t* vt = (bf16_t*)take(G * NB * 2);

    k_split_wt<<<dim3((unsigned)(NW / 4 / 256)), 256, 0, stream>>>(w, wth, wtl);

    for (int g0 = 0; g0 < 16; g0 += G) {
        const int Gc = (16 - g0 < G) ? (16 - g0) : G;
        const size_t base = (size_t)g0 * NB;
        k_split_x<<<dim3((unsigned)(Gc * NB / 4 / 256)), 256, 0, stream>>>(
            x + base, xh, xl, (int)(Gc * NB));
        k_qkv<<<dim3(12, 16 * Gc), 256, 0, stream>>>(
            xh, xl, wth, wtl, qf, kh, kl, vt);
        k_flash<<<dim3(32, Gc), 512, 0, stream>>>(
            qf, kh, kl, vt, out + base);
    }
}